// Round 10
// baseline (821.014 us; speedup 1.0000x reference)
//
#include <hip/hip_runtime.h>
#include <hip/hip_bf16.h>

#define VOCAB 32000
#define EMB   128
#define HID   128
#define BB    8
#define SS    1024

typedef __bf16 bf16x8_t __attribute__((ext_vector_type(8)));
typedef float  f32x4_t  __attribute__((ext_vector_type(4)));

__device__ __forceinline__ float dpp_xor1(float x) {
    return __int_as_float(__builtin_amdgcn_update_dpp(
        0, __float_as_int(x), 0xB1, 0xF, 0xF, true));   // quad_perm(1,0,3,2)
}
__device__ __forceinline__ float dpp_xor2(float x) {
    return __int_as_float(__builtin_amdgcn_update_dpp(
        0, __float_as_int(x), 0x4E, 0xF, 0xF, true));   // quad_perm(2,3,0,1)
}

// ---------------------------------------------------------------------------
// Kernel A: xp[b,s,h] = sum_e emb[x[b,s],e] * W_ih[h,e] + b_ih[h] + b_hh[h]
// ---------------------------------------------------------------------------
__global__ __launch_bounds__(512) void xproj_kernel(
    const int* __restrict__ x, const float* __restrict__ emb,
    const float* __restrict__ W_ih, const float* __restrict__ b_ih,
    const float* __restrict__ b_hh, float* __restrict__ xp)
{
    const int t  = threadIdx.x;
    const int h  = t >> 2;
    const int ks = t & 3;

    float w[32];
    {
        const float* wr = W_ih + h * EMB + ks * 32;
        #pragma unroll
        for (int i = 0; i < 32; i += 4) {
            float4 v = *(const float4*)(wr + i);
            w[i] = v.x; w[i+1] = v.y; w[i+2] = v.z; w[i+3] = v.w;
        }
    }
    const float bias = b_ih[h] + b_hh[h];

    __shared__ float el[2][EMB];
    const int base = blockIdx.x * 32;

    float4 v = make_float4(0.f, 0.f, 0.f, 0.f);
    if (t < 32) v = *(const float4*)(emb + (size_t)x[base] * EMB + t * 4);

    for (int r = 0; r < 32; ++r) {
        if (t < 32) *(float4*)(&el[r & 1][t * 4]) = v;
        __syncthreads();
        if (t < 32 && r + 1 < 32)
            v = *(const float4*)(emb + (size_t)x[base + r + 1] * EMB + t * 4);

        float a0 = 0.f, a1 = 0.f, a2 = 0.f, a3 = 0.f;
        const float* e = &el[r & 1][ks * 32];
        #pragma unroll
        for (int c = 0; c < 8; ++c) {
            float4 hv = *(const float4*)(e + c * 4);
            a0 = fmaf(w[c*4+0], hv.x, a0);
            a1 = fmaf(w[c*4+1], hv.y, a1);
            a2 = fmaf(w[c*4+2], hv.z, a2);
            a3 = fmaf(w[c*4+3], hv.w, a3);
        }
        float sum = (a0 + a1) + (a2 + a3);
        sum += __shfl_xor(sum, 1);
        sum += __shfl_xor(sum, 2);
        if (ks == 0) xp[(size_t)(base + r) * HID + h] = bias + sum;
    }
}

// ---------------------------------------------------------------------------
// Kernel D: fp32 -> bf16 convert for fc_W
// ---------------------------------------------------------------------------
__global__ __launch_bounds__(256) void convert_bf16_kernel(
    const float* __restrict__ in, __hip_bfloat16* __restrict__ out)
{
    const size_t i = ((size_t)blockIdx.x * 256 + threadIdx.x) * 8;
    float4 a = *(const float4*)(in + i);
    float4 b = *(const float4*)(in + i + 4);
    union { __hip_bfloat16 h[8]; uint4 u; } p;
    p.h[0] = __float2bfloat16(a.x); p.h[1] = __float2bfloat16(a.y);
    p.h[2] = __float2bfloat16(a.z); p.h[3] = __float2bfloat16(a.w);
    p.h[4] = __float2bfloat16(b.x); p.h[5] = __float2bfloat16(b.y);
    p.h[6] = __float2bfloat16(b.z); p.h[7] = __float2bfloat16(b.w);
    *(uint4*)(out + i) = p.u;
}

// ---------------------------------------------------------------------------
// Kernel B: recurrence, 2-wave minimal-DS design (R8/R9 conclusion: per-CU
// DS instruction count dominates the step; barrier itself is ~free).
// 8 blocks x 128 threads (2 waves). Wave w owns rows [64w, 64w+64).
// lane l: ks = l&3 (32-float k-slice), jg = l>>2 (4 rows: 4jg..4jg+3 local).
//  - per CU per step: 16 ds_read_b128 (broadcast, conflict-free via
//    word(k) = k + (k>>5)*8 padding) + 2 ds_write_b32 = 18 DS instr.
//  - reduce over 4 k-lanes: dpp xor1 + xor2; lane l then finalizes exactly
//    row w*64+l (symmetric: 1 xp float, 1 tanh, 1 LDS write, 1 bf16 store
//    per lane -> zero divergence).
//  - double-buffered h; one lgkmcnt(0)+s_barrier per step; vmem never
//    drained in-loop; xp prefetched 4-deep in named registers.
// ---------------------------------------------------------------------------
__global__ __launch_bounds__(128, 1) void rnn_kernel(
    const float* __restrict__ xp, const float* __restrict__ W_hh,
    __hip_bfloat16* __restrict__ hs_bf16, float* __restrict__ hidden_out)
{
    const int b  = blockIdx.x;
    const int t  = threadIdx.x;      // 0..127
    const int w  = t >> 6;           // wave 0/1
    const int l  = t & 63;
    const int ks = l & 3;
    const int jg = l >> 2;           // 0..15
    const int r0 = w * 64 + jg * 4;  // this lane's 4 global rows
    const int j  = w * 64 + l;       // the row this lane finalizes

    // W slice: 4 rows x 32 k = 32 f32x4 = 128 VGPR
    f32x4_t wv[4][8];
    #pragma unroll
    for (int r = 0; r < 4; ++r) {
        const float* src = W_hh + (size_t)(r0 + r) * HID + ks * 32;
        #pragma unroll
        for (int c = 0; c < 8; ++c) wv[r][c] = *(const f32x4_t*)(src + c * 4);
    }
    asm volatile("" :
        "+v"(wv[0][0]), "+v"(wv[0][1]), "+v"(wv[0][2]), "+v"(wv[0][3]),
        "+v"(wv[0][4]), "+v"(wv[0][5]), "+v"(wv[0][6]), "+v"(wv[0][7]),
        "+v"(wv[1][0]), "+v"(wv[1][1]), "+v"(wv[1][2]), "+v"(wv[1][3]),
        "+v"(wv[1][4]), "+v"(wv[1][5]), "+v"(wv[1][6]), "+v"(wv[1][7]),
        "+v"(wv[2][0]), "+v"(wv[2][1]), "+v"(wv[2][2]), "+v"(wv[2][3]),
        "+v"(wv[2][4]), "+v"(wv[2][5]), "+v"(wv[2][6]), "+v"(wv[2][7]),
        "+v"(wv[3][0]), "+v"(wv[3][1]), "+v"(wv[3][2]), "+v"(wv[3][3]),
        "+v"(wv[3][4]), "+v"(wv[3][5]), "+v"(wv[3][6]), "+v"(wv[3][7]));

    // padded h: word(k) = k + (k>>5)*8  -> the 4 k-slices start at banks
    // {0,8,16,24}; writes hit each bank exactly 2x per wave (free).
    __shared__ float hbuf[2][160];
    hbuf[0][t] = 0.f;
    if (t < 32) hbuf[0][128 + t] = 0.f;

    const float*           xpj = xp      + (size_t)b * SS * HID + j;
    __hip_bfloat16*        hsj = hs_bf16 + (size_t)b * SS * HID + j;
    const int rbase = ks * 40;
    const int wword = j + ((j >> 5) << 3);

    float xA0 = xpj[0];
    float xA1 = xpj[(size_t)1 * HID];
    float xA2 = xpj[(size_t)2 * HID];
    float xA3 = xpj[(size_t)3 * HID];
    float xB0, xB1, xB2, xB3;
    __syncthreads();

#define RNN_STEP(P, XS, STEPI)                                               \
    {                                                                        \
        const float* hc = hbuf[P];                                           \
        f32x4_t hv0 = *(const f32x4_t*)(hc + rbase);                         \
        f32x4_t hv1 = *(const f32x4_t*)(hc + rbase + 4);                     \
        f32x4_t hv2 = *(const f32x4_t*)(hc + rbase + 8);                     \
        f32x4_t hv3 = *(const f32x4_t*)(hc + rbase + 12);                    \
        f32x4_t hv4 = *(const f32x4_t*)(hc + rbase + 16);                    \
        f32x4_t hv5 = *(const f32x4_t*)(hc + rbase + 20);                    \
        f32x4_t hv6 = *(const f32x4_t*)(hc + rbase + 24);                    \
        f32x4_t hv7 = *(const f32x4_t*)(hc + rbase + 28);                    \
        f32x4_t a0 = wv[0][0] * hv0;                                         \
        f32x4_t a1 = wv[1][0] * hv0;                                         \
        f32x4_t a2 = wv[2][0] * hv0;                                         \
        f32x4_t a3 = wv[3][0] * hv0;                                         \
        a0 += wv[0][1] * hv1; a1 += wv[1][1] * hv1;                          \
        a2 += wv[2][1] * hv1; a3 += wv[3][1] * hv1;                          \
        a0 += wv[0][2] * hv2; a1 += wv[1][2] * hv2;                          \
        a2 += wv[2][2] * hv2; a3 += wv[3][2] * hv2;                          \
        a0 += wv[0][3] * hv3; a1 += wv[1][3] * hv3;                          \
        a2 += wv[2][3] * hv3; a3 += wv[3][3] * hv3;                          \
        a0 += wv[0][4] * hv4; a1 += wv[1][4] * hv4;                          \
        a2 += wv[2][4] * hv4; a3 += wv[3][4] * hv4;                          \
        a0 += wv[0][5] * hv5; a1 += wv[1][5] * hv5;                          \
        a2 += wv[2][5] * hv5; a3 += wv[3][5] * hv5;                          \
        a0 += wv[0][6] * hv6; a1 += wv[1][6] * hv6;                          \
        a2 += wv[2][6] * hv6; a3 += wv[3][6] * hv6;                          \
        a0 += wv[0][7] * hv7; a1 += wv[1][7] * hv7;                          \
        a2 += wv[2][7] * hv7; a3 += wv[3][7] * hv7;                          \
        float s0 = (a0.x + a0.y) + (a0.z + a0.w);                            \
        float s1 = (a1.x + a1.y) + (a1.z + a1.w);                            \
        float s2 = (a2.x + a2.y) + (a2.z + a2.w);                            \
        float s3 = (a3.x + a3.y) + (a3.z + a3.w);                            \
        s0 += dpp_xor1(s0); s1 += dpp_xor1(s1);                              \
        s2 += dpp_xor1(s2); s3 += dpp_xor1(s3);                              \
        s0 += dpp_xor2(s0); s1 += dpp_xor2(s1);                              \
        s2 += dpp_xor2(s2); s3 += dpp_xor2(s3);                              \
        const float sm = (ks & 2) ? ((ks & 1) ? s3 : s2)                     \
                                  : ((ks & 1) ? s1 : s0);                    \
        const float zz = (XS) + sm;                                          \
        const float ee = __expf(2.0f * zz);                                  \
        const float hn = 1.0f - 2.0f * __builtin_amdgcn_rcpf(ee + 1.0f);     \
        hbuf[1 - (P)][wword] = hn;                                           \
        hsj[(size_t)(STEPI) * HID] = __float2bfloat16(hn);                   \
        if ((STEPI) == SS - 1) hidden_out[b * HID + j] = hn;                 \
        asm volatile("s_waitcnt lgkmcnt(0)" ::: "memory");                   \
        __builtin_amdgcn_s_barrier();                                        \
    }

    for (int sb = 0; sb < SS / 8; ++sb) {
        const int base = sb * 8;
        xB0 = xpj[(size_t)(base + 4) * HID];
        xB1 = xpj[(size_t)(base + 5) * HID];
        xB2 = xpj[(size_t)(base + 6) * HID];
        xB3 = xpj[(size_t)(base + 7) * HID];
        RNN_STEP(0, xA0, base + 0)
        RNN_STEP(1, xA1, base + 1)
        RNN_STEP(0, xA2, base + 2)
        RNN_STEP(1, xA3, base + 3)
        if (base + 8 < SS) {
            xA0 = xpj[(size_t)(base + 8)  * HID];
            xA1 = xpj[(size_t)(base + 9)  * HID];
            xA2 = xpj[(size_t)(base + 10) * HID];
            xA3 = xpj[(size_t)(base + 11) * HID];
        }
        RNN_STEP(0, xB0, base + 4)
        RNN_STEP(1, xB1, base + 5)
        RNN_STEP(0, xB2, base + 6)
        RNN_STEP(1, xB3, base + 7)
    }
#undef RNN_STEP
}

// ---------------------------------------------------------------------------
// Kernel C: logits = A @ Wb^T + fc_b. (R5-validated: at HBM write floor.)
// ---------------------------------------------------------------------------
__global__ __launch_bounds__(256) void fc_kernel(
    const __hip_bfloat16* __restrict__ A, const __hip_bfloat16* __restrict__ Wb,
    const float* __restrict__ fc_b, float* __restrict__ C)
{
    const int lane = threadIdx.x & 63;
    const int wv   = threadIdx.x >> 6;
    const int wm   = wv >> 1;
    const int wn   = wv & 1;

    const int bid = blockIdx.x;
    const int wg  = (bid & 7) * 2000 + (bid >> 3);
    const int mb  = wg / 250;
    const int nb  = wg % 250;

    const int m0 = mb * 128 + wm * 64;
    const int n0 = nb * 128 + wn * 64;
    const int lr = lane & 15;
    const int kq = lane >> 4;

    const __hip_bfloat16* Arow = A  + (size_t)(m0 + lr) * HID + kq * 8;
    const __hip_bfloat16* Wrow = Wb + (size_t)(n0 + lr) * HID + kq * 8;

    f32x4_t acc[4][4];
    #pragma unroll
    for (int i = 0; i < 4; ++i)
        #pragma unroll
        for (int jj = 0; jj < 4; ++jj)
            acc[i][jj] = (f32x4_t){0.f, 0.f, 0.f, 0.f};

    bf16x8_t af[2][4], bw[2][4];
    #pragma unroll
    for (int mt = 0; mt < 4; ++mt) af[0][mt] = *(const bf16x8_t*)(Arow + mt * 16 * HID);
    #pragma unroll
    for (int nt = 0; nt < 4; ++nt) bw[0][nt] = *(const bf16x8_t*)(Wrow + nt * 16 * HID);

    #pragma unroll
    for (int kk = 0; kk < 4; ++kk) {
        const int cur = kk & 1, nxt = cur ^ 1;
        if (kk < 3) {
            const int off = (kk + 1) * 32;
            #pragma unroll
            for (int mt = 0; mt < 4; ++mt)
                af[nxt][mt] = *(const bf16x8_t*)(Arow + mt * 16 * HID + off);
            #pragma unroll
            for (int nt = 0; nt < 4; ++nt)
                bw[nxt][nt] = *(const bf16x8_t*)(Wrow + nt * 16 * HID + off);
        }
        #pragma unroll
        for (int mt = 0; mt < 4; ++mt)
            #pragma unroll
            for (int nt = 0; nt < 4; ++nt)
                acc[mt][nt] = __builtin_amdgcn_mfma_f32_16x16x32_bf16(
                    bw[cur][nt], af[cur][mt], acc[mt][nt], 0, 0, 0);
    }

    const int vq = kq * 4;
    #pragma unroll
    for (int nt = 0; nt < 4; ++nt) {
        const int v0 = n0 + nt * 16 + vq;
        float4 fb = *(const float4*)(fc_b + v0);
        const f32x4_t fbv = {fb.x, fb.y, fb.z, fb.w};
        #pragma unroll
        for (int mt = 0; mt < 4; ++mt) {
            const int row = m0 + mt * 16 + lr;
            *(f32x4_t*)(C + (size_t)row * VOCAB + v0) = acc[mt][nt] + fbv;
        }
    }
}

// ---------------------------------------------------------------------------
extern "C" void kernel_launch(void* const* d_in, const int* in_sizes, int n_in,
                              void* d_out, int out_size, void* d_ws, size_t ws_size,
                              hipStream_t stream)
{
    const int*   x    = (const int*)  d_in[0];
    const float* emb  = (const float*)d_in[1];
    const float* W_ih = (const float*)d_in[2];
    const float* b_ih = (const float*)d_in[3];
    const float* W_hh = (const float*)d_in[4];
    const float* b_hh = (const float*)d_in[5];
    const float* fc_W = (const float*)d_in[6];
    const float* fc_b = (const float*)d_in[7];

    float* logits = (float*)d_out;
    float* hidden = logits + (size_t)BB * SS * VOCAB;

    char* ws = (char*)d_ws;
    float*           xpb = (float*)ws;                               // 4,194,304 B
    __hip_bfloat16*  hsb = (__hip_bfloat16*)(ws + 4194304);          // 2,097,152 B
    __hip_bfloat16*  fwb = (__hip_bfloat16*)(ws + 6291456);          // 8,192,000 B

    xproj_kernel<<<dim3(256), dim3(512), 0, stream>>>(x, emb, W_ih, b_ih, b_hh, xpb);
    convert_bf16_kernel<<<dim3(2000), dim3(256), 0, stream>>>(fc_W, fwb);
    rnn_kernel<<<dim3(8), dim3(128), 0, stream>>>(xpb, W_hh, hsb, hidden);
    fc_kernel<<<dim3(16000), dim3(256), 0, stream>>>(hsb, fwb, fc_b, logits);
}

// Round 11
// 556.709 us; speedup vs baseline: 1.4748x; 1.4748x over previous
//
#include <hip/hip_runtime.h>
#include <hip/hip_bf16.h>

#define VOCAB 32000
#define EMB   128
#define HID   128
#define BB    8
#define SS    1024

typedef __bf16 bf16x8_t __attribute__((ext_vector_type(8)));
typedef float  f32x4_t  __attribute__((ext_vector_type(4)));

__device__ __forceinline__ float dpp_xor1(float x) {
    return __int_as_float(__builtin_amdgcn_update_dpp(
        0, __float_as_int(x), 0xB1, 0xF, 0xF, true));   // quad_perm(1,0,3,2)
}
__device__ __forceinline__ float dpp_xor2(float x) {
    return __int_as_float(__builtin_amdgcn_update_dpp(
        0, __float_as_int(x), 0x4E, 0xF, 0xF, true));   // quad_perm(2,3,0,1)
}

// ---------------------------------------------------------------------------
// Kernel A: xp[b,s,h] = sum_e emb[x[b,s],e] * W_ih[h,e] + b_ih[h] + b_hh[h]
// ---------------------------------------------------------------------------
__global__ __launch_bounds__(512) void xproj_kernel(
    const int* __restrict__ x, const float* __restrict__ emb,
    const float* __restrict__ W_ih, const float* __restrict__ b_ih,
    const float* __restrict__ b_hh, float* __restrict__ xp)
{
    const int t  = threadIdx.x;
    const int h  = t >> 2;
    const int ks = t & 3;

    float w[32];
    {
        const float* wr = W_ih + h * EMB + ks * 32;
        #pragma unroll
        for (int i = 0; i < 32; i += 4) {
            float4 v = *(const float4*)(wr + i);
            w[i] = v.x; w[i+1] = v.y; w[i+2] = v.z; w[i+3] = v.w;
        }
    }
    const float bias = b_ih[h] + b_hh[h];

    __shared__ float el[2][EMB];
    const int base = blockIdx.x * 32;

    float4 v = make_float4(0.f, 0.f, 0.f, 0.f);
    if (t < 32) v = *(const float4*)(emb + (size_t)x[base] * EMB + t * 4);

    for (int r = 0; r < 32; ++r) {
        if (t < 32) *(float4*)(&el[r & 1][t * 4]) = v;
        __syncthreads();
        if (t < 32 && r + 1 < 32)
            v = *(const float4*)(emb + (size_t)x[base + r + 1] * EMB + t * 4);

        float a0 = 0.f, a1 = 0.f, a2 = 0.f, a3 = 0.f;
        const float* e = &el[r & 1][ks * 32];
        #pragma unroll
        for (int c = 0; c < 8; ++c) {
            float4 hv = *(const float4*)(e + c * 4);
            a0 = fmaf(w[c*4+0], hv.x, a0);
            a1 = fmaf(w[c*4+1], hv.y, a1);
            a2 = fmaf(w[c*4+2], hv.z, a2);
            a3 = fmaf(w[c*4+3], hv.w, a3);
        }
        float sum = (a0 + a1) + (a2 + a3);
        sum += __shfl_xor(sum, 1);
        sum += __shfl_xor(sum, 2);
        if (ks == 0) xp[(size_t)(base + r) * HID + h] = bias + sum;
    }
}

// ---------------------------------------------------------------------------
// Kernel D: fp32 -> bf16 convert for fc_W
// ---------------------------------------------------------------------------
__global__ __launch_bounds__(256) void convert_bf16_kernel(
    const float* __restrict__ in, __hip_bfloat16* __restrict__ out)
{
    const size_t i = ((size_t)blockIdx.x * 256 + threadIdx.x) * 8;
    float4 a = *(const float4*)(in + i);
    float4 b = *(const float4*)(in + i + 4);
    union { __hip_bfloat16 h[8]; uint4 u; } p;
    p.h[0] = __float2bfloat16(a.x); p.h[1] = __float2bfloat16(a.y);
    p.h[2] = __float2bfloat16(a.z); p.h[3] = __float2bfloat16(a.w);
    p.h[4] = __float2bfloat16(b.x); p.h[5] = __float2bfloat16(b.y);
    p.h[6] = __float2bfloat16(b.z); p.h[7] = __float2bfloat16(b.w);
    *(uint4*)(out + i) = p.u;
}

// ---------------------------------------------------------------------------
// Mega-kernel: 256 blocks x 256 threads.
//   blocks 0..7   : R7-exact RNN producer (4 waves, best measured: 420us).
//                   Every 128 steps: vmcnt(0) + barrier + t0 RELEASE-store of
//                   prog[b] (flushes XCD L2 -> hs visible at L3).
//   blocks 8..255 : fc consumers. Poll with RELAXED agent fetch_add(0) —
//                   memory-side atomic: always fresh, NO cache invalidation
//                   (R3's failure was an acquire per poll). ONE acquire fence
//                   per time-chunk after observation, then ~8 fc tiles.
// Co-residency: 256 blocks <= capacity -> producers never starved; consumers
// spin with s_sleep. Deterministic: same work every call.
// ---------------------------------------------------------------------------
__global__ __launch_bounds__(256) void mega_kernel(
    const float* __restrict__ xp, const float* __restrict__ W_hh,
    __hip_bfloat16* __restrict__ hs_bf16, float* __restrict__ hidden_out,
    const __hip_bfloat16* __restrict__ Wb, const float* __restrict__ fc_b,
    float* __restrict__ C, unsigned int* __restrict__ prog)
{
    const int bid = blockIdx.x;

    if (bid < BB) {
        // ----------------- RNN producer (batch = bid), R7-exact -----------
        const int b  = bid;
        const int t  = threadIdx.x;
        const int w  = t >> 6;
        const int l  = t & 63;
        const int ks = l & 3;
        const int g  = l >> 2;
        const int jb = w * 16 + g;

        f32x4_t wr[2][8];
        #pragma unroll
        for (int m = 0; m < 2; ++m) {
            const float* src = W_hh + (size_t)(jb + 64 * m) * HID + ks * 32;
            #pragma unroll
            for (int i = 0; i < 8; ++i) wr[m][i] = *(const f32x4_t*)(src + i * 4);
        }

        __shared__ float hbuf[2][160];        // padded: word(k) = k + (k>>4)*4
        if (t < 160) hbuf[0][t] = 0.f;

        const float* xpb = xp + (size_t)b * SS * HID;
        const bool  wrt  = (ks == 0);
        const int rbase = ks * 40;

        float xsA[8][2], xsB[8][2];
        if (wrt) {
            #pragma unroll
            for (int u = 0; u < 8; ++u) {
                xsA[u][0] = xpb[(size_t)u * HID + jb];
                xsA[u][1] = xpb[(size_t)u * HID + jb + 64];
            }
        }
        __syncthreads();

#define RNN_SUPERSTEP(XC, XN, BASE)                                          \
    {                                                                        \
        const int nbase_ = (BASE) + 8;                                       \
        if (wrt && nbase_ < SS) {                                            \
            _Pragma("unroll")                                                \
            for (int u = 0; u < 8; ++u) {                                    \
                XN[u][0] = xpb[(size_t)(nbase_ + u) * HID + jb];             \
                XN[u][1] = xpb[(size_t)(nbase_ + u) * HID + jb + 64];        \
            }                                                                \
        }                                                                    \
        _Pragma("unroll")                                                    \
        for (int u = 0; u < 8; ++u) {                                        \
            const int step_ = (BASE) + u;                                    \
            const float* hc_ = hbuf[u & 1];                                  \
            f32x4_t hv[8];                                                   \
            _Pragma("unroll")                                                \
            for (int i = 0; i < 4; ++i)                                      \
                hv[i] = *(const f32x4_t*)(hc_ + rbase + i * 4);              \
            _Pragma("unroll")                                                \
            for (int i = 4; i < 8; ++i)                                      \
                hv[i] = *(const f32x4_t*)(hc_ + rbase + 4 + i * 4);          \
            f32x4_t a0 = {0.f,0.f,0.f,0.f}, a1 = a0, c0 = a0, c1 = a0;       \
            _Pragma("unroll")                                                \
            for (int i = 0; i < 4; ++i) {                                    \
                a0 += wr[0][i]   * hv[i];                                    \
                a1 += wr[0][i+4] * hv[i+4];                                  \
                c0 += wr[1][i]   * hv[i];                                    \
                c1 += wr[1][i+4] * hv[i+4];                                  \
            }                                                                \
            f32x4_t av = a0 + a1, cv = c0 + c1;                              \
            float s0 = (av.x + av.y) + (av.z + av.w);                        \
            float s1 = (cv.x + cv.y) + (cv.z + cv.w);                        \
            s0 += dpp_xor1(s0);  s0 += dpp_xor2(s0);                         \
            s1 += dpp_xor1(s1);  s1 += dpp_xor2(s1);                         \
            if (wrt) {                                                       \
                const float z0 = XC[u][0] + s0;                              \
                const float e0 = __expf(2.0f * z0);                          \
                const float h0 = 1.0f - 2.0f * __builtin_amdgcn_rcpf(e0 + 1.0f); \
                const float z1 = XC[u][1] + s1;                              \
                const float e1 = __expf(2.0f * z1);                          \
                const float h1 = 1.0f - 2.0f * __builtin_amdgcn_rcpf(e1 + 1.0f); \
                const int j0 = jb, j1 = jb + 64;                             \
                hbuf[(u + 1) & 1][j0 + ((j0 >> 4) << 2)] = h0;               \
                hbuf[(u + 1) & 1][j1 + ((j1 >> 4) << 2)] = h1;               \
                hs_bf16[((size_t)b * SS + step_) * HID + j0] = __float2bfloat16(h0); \
                hs_bf16[((size_t)b * SS + step_) * HID + j1] = __float2bfloat16(h1); \
                if (step_ == SS - 1) {                                       \
                    hidden_out[b * HID + j0] = h0;                           \
                    hidden_out[b * HID + j1] = h1;                           \
                }                                                            \
            }                                                                \
            asm volatile("s_waitcnt lgkmcnt(0)" ::: "memory");               \
            __builtin_amdgcn_s_barrier();                                    \
        }                                                                    \
    }

        for (int chunk = 0; chunk < 8; ++chunk) {
            for (int sb2 = 0; sb2 < 8; ++sb2) {
                const int base = chunk * 128 + sb2 * 16;
                RNN_SUPERSTEP(xsA, xsB, base);
                RNN_SUPERSTEP(xsB, xsA, base + 8);
            }
            // chunk done: drain hs stores, then release the flag.
            asm volatile("s_waitcnt vmcnt(0)" ::: "memory");
            __builtin_amdgcn_s_barrier();
            if (t == 0)
                __hip_atomic_store(&prog[b], (unsigned)(chunk + 1),
                                   __ATOMIC_RELEASE, __HIP_MEMORY_SCOPE_AGENT);
        }
#undef RNN_SUPERSTEP
    } else {
        // ----------------- FC consumer -----------------
        const int cid  = bid - BB;          // 0..247
        const int NC   = 256 - BB;          // 248
        const int t    = threadIdx.x;
        const int lane = t & 63;
        const int cw   = t >> 6;
        const int wm   = cw >> 1;
        const int wn   = cw & 1;
        const int lr   = lane & 15;
        const int kq   = lane >> 4;

        for (int tc = 0; tc < 8; ++tc) {
            if (t == 0) {
                for (int b2 = 0; b2 < BB; ++b2) {
                    // RELAXED memory-side RMW poll: fresh value, no cache inv.
                    while (__hip_atomic_fetch_add(&prog[b2], 0u,
                               __ATOMIC_RELAXED, __HIP_MEMORY_SCOPE_AGENT)
                           < (unsigned)(tc + 1))
                        __builtin_amdgcn_s_sleep(32);
                }
            }
            __syncthreads();
            // One acquire fence per chunk: invalidate stale L1/L2 once.
            __builtin_amdgcn_fence(__ATOMIC_ACQUIRE, "agent");

            for (int i = cid; i < 2000; i += NC) {
                const int b2 = i / 250;
                const int nb = i % 250;
                const int mb = b2 * 8 + tc;
                const int m0 = mb * 128 + wm * 64;
                const int n0 = nb * 128 + wn * 64;

                const __hip_bfloat16* Arow = hs_bf16 + (size_t)(m0 + lr) * HID + kq * 8;
                const __hip_bfloat16* Wrow = Wb      + (size_t)(n0 + lr) * HID + kq * 8;

                f32x4_t acc[4][4];
                #pragma unroll
                for (int ii = 0; ii < 4; ++ii)
                    #pragma unroll
                    for (int jj = 0; jj < 4; ++jj)
                        acc[ii][jj] = (f32x4_t){0.f, 0.f, 0.f, 0.f};

                bf16x8_t af[2][4], bw[2][4];
                #pragma unroll
                for (int mt = 0; mt < 4; ++mt)
                    af[0][mt] = *(const bf16x8_t*)(Arow + mt * 16 * HID);
                #pragma unroll
                for (int nt = 0; nt < 4; ++nt)
                    bw[0][nt] = *(const bf16x8_t*)(Wrow + nt * 16 * HID);

                #pragma unroll
                for (int kk = 0; kk < 4; ++kk) {
                    const int cur = kk & 1, nxt = cur ^ 1;
                    if (kk < 3) {
                        const int off = (kk + 1) * 32;
                        #pragma unroll
                        for (int mt = 0; mt < 4; ++mt)
                            af[nxt][mt] = *(const bf16x8_t*)(Arow + mt * 16 * HID + off);
                        #pragma unroll
                        for (int nt = 0; nt < 4; ++nt)
                            bw[nxt][nt] = *(const bf16x8_t*)(Wrow + nt * 16 * HID + off);
                    }
                    #pragma unroll
                    for (int mt = 0; mt < 4; ++mt)
                        #pragma unroll
                        for (int nt = 0; nt < 4; ++nt)
                            acc[mt][nt] = __builtin_amdgcn_mfma_f32_16x16x32_bf16(
                                bw[cur][nt], af[cur][mt], acc[mt][nt], 0, 0, 0);
                }

                // D (swapped): reg axis = 4 consecutive vocab cols, lane&15 = m row
                const int vq = kq * 4;
                #pragma unroll
                for (int nt = 0; nt < 4; ++nt) {
                    const int v0 = n0 + nt * 16 + vq;
                    float4 fb = *(const float4*)(fc_b + v0);
                    const f32x4_t fbv = {fb.x, fb.y, fb.z, fb.w};
                    #pragma unroll
                    for (int mt = 0; mt < 4; ++mt) {
                        const int row = m0 + mt * 16 + lr;
                        *(f32x4_t*)(C + (size_t)row * VOCAB + v0) = acc[mt][nt] + fbv;
                    }
                }
            }
        }
    }
}

// ---------------------------------------------------------------------------
extern "C" void kernel_launch(void* const* d_in, const int* in_sizes, int n_in,
                              void* d_out, int out_size, void* d_ws, size_t ws_size,
                              hipStream_t stream)
{
    const int*   x    = (const int*)  d_in[0];
    const float* emb  = (const float*)d_in[1];
    const float* W_ih = (const float*)d_in[2];
    const float* b_ih = (const float*)d_in[3];
    const float* W_hh = (const float*)d_in[4];
    const float* b_hh = (const float*)d_in[5];
    const float* fc_W = (const float*)d_in[6];
    const float* fc_b = (const float*)d_in[7];

    float* logits = (float*)d_out;
    float* hidden = logits + (size_t)BB * SS * VOCAB;

    char* ws = (char*)d_ws;
    float*           xpb = (float*)ws;                               // 4,194,304 B
    __hip_bfloat16*  hsb = (__hip_bfloat16*)(ws + 4194304);          // 2,097,152 B
    __hip_bfloat16*  fwb = (__hip_bfloat16*)(ws + 6291456);          // 8,192,000 B
    unsigned int*    prg = (unsigned int*)(ws + 14483456);           // 32 B

    hipMemsetAsync(prg, 0, 64, stream);
    xproj_kernel<<<dim3(256), dim3(512), 0, stream>>>(x, emb, W_ih, b_ih, b_hh, xpb);
    convert_bf16_kernel<<<dim3(2000), dim3(256), 0, stream>>>(fc_W, fwb);
    mega_kernel<<<dim3(256), dim3(256), 0, stream>>>(xpb, W_hh, hsb, hidden,
                                                     fwb, fc_b, logits, prg);
}